// Round 3
// baseline (374.917 us; speedup 1.0000x reference)
//
#include <hip/hip_runtime.h>

// tanh-attention (no softmax): O = tanh(0.1/sqrt(24) * Q K^T) V
// B=2,H=8 -> 16 heads; S=2048; D=24 (padded to 32 for MFMA K-dim).
// Swapped QK^T (S^T = K*Q^T) keeps every P value lane-local for the
// elementwise tanh; a within-wave shuffle regroups P^T into the PV A-frag.

#define S_LEN 2048
#define HD 24
#define CMUL 0.02041241452319315f  // 0.1 / sqrt(24)

typedef short short8 __attribute__((ext_vector_type(8)));
typedef float f32x4 __attribute__((ext_vector_type(4)));
typedef unsigned int uint4v __attribute__((ext_vector_type(4)));

static __device__ __forceinline__ unsigned int f2bf_u(float f) {
  // round-to-nearest-even fp32 -> bf16 (bits in low 16)
  unsigned int u = __float_as_uint(f);
  u += 0x7FFFu + ((u >> 16) & 1u);
  return u >> 16;
}

static __device__ __forceinline__ float tanh_fast(float m) {
  m = fminf(fmaxf(m, -9.f), 9.f);
  float t = __expf(2.f * m);  // e^{2m}
  return (t - 1.f) * __builtin_amdgcn_rcpf(t + 1.f);
}

// Load an A/B fragment row: lane holds row `lr`, d = 8*lg + j (j=0..7).
// D=24, so group lg==3 (d0=24..31) is the zero pad.
static __device__ __forceinline__ short8 load_frag24(const float* rowp, int lg) {
  short8 f = {0, 0, 0, 0, 0, 0, 0, 0};
  if (lg < 3) {
    const float4 x = *reinterpret_cast<const float4*>(rowp);
    const float4 y = *reinterpret_cast<const float4*>(rowp + 4);
    f[0] = (short)f2bf_u(x.x); f[1] = (short)f2bf_u(x.y);
    f[2] = (short)f2bf_u(x.z); f[3] = (short)f2bf_u(x.w);
    f[4] = (short)f2bf_u(y.x); f[5] = (short)f2bf_u(y.y);
    f[6] = (short)f2bf_u(y.z); f[7] = (short)f2bf_u(y.w);
  }
  return f;
}

extern "C" __global__ __launch_bounds__(256, 2) void attn_tanh_fused(
    const float* __restrict__ Qg, const float* __restrict__ Kg,
    const float* __restrict__ Vg, float* __restrict__ Og) {
  __shared__ float part[4][32][32];  // 16 KiB: per-wave fp32 partial O tiles

  const int tid = threadIdx.x;
  const int w   = tid >> 6;   // wave 0..3 -> KV chunk
  const int l   = tid & 63;
  const int lr  = l & 15;     // row-in-16
  const int lg  = l >> 4;     // lane group 0..3
  const int bh  = blockIdx.y;
  const int q0  = blockIdx.x * 32;

  const float* Qb = Qg + bh * S_LEN * HD;
  const float* Kb = Kg + bh * S_LEN * HD;
  const float* Vb = Vg + bh * S_LEN * HD;

  // Q fragments for two 16-row q-subtiles (held all kernel)
  short8 qf[2];
#pragma unroll
  for (int sub = 0; sub < 2; ++sub)
    qf[sub] = load_frag24(Qb + (q0 + sub * 16 + lr) * HD + lg * 8, lg);

  const f32x4 zero4 = {0.f, 0.f, 0.f, 0.f};
  f32x4 acc[2][2];  // [q-sub][d-col-tile(0:0..15,1:16..23)]
#pragma unroll
  for (int i = 0; i < 2; ++i)
#pragma unroll
    for (int j = 0; j < 2; ++j) acc[i][j] = zero4;

  const int kv0  = w * (S_LEN / 4);
  const int srcA = lr + ((lg & 1) << 5);  // quad-regroup shuffle sources
  const int srcB = srcA + 16;
  const bool hi  = (lg >> 1) != 0;

#pragma unroll 2
  for (int kt = kv0; kt < kv0 + S_LEN / 4; kt += 32) {
    // K fragments: two 16-row halves of this 32-kv tile
    short8 kf0 = load_frag24(Kb + (kt + lr) * HD + lg * 8, lg);
    short8 kf1 = load_frag24(Kb + (kt + 16 + lr) * HD + lg * 8, lg);

    // V B-fragments for 16x16x32: lane holds V[kt + 8*lg + j][dcol], j=0..7
    short8 vf0, vf1;
    {
      const float* vp = Vb + (kt + lg * 8) * HD;
      const int c1 = lr + 16;
#pragma unroll
      for (int j = 0; j < 8; ++j) {
        vf0[j] = (short)f2bf_u(vp[j * HD + lr]);
        vf1[j] = (short)(c1 < HD ? f2bf_u(vp[j * HD + c1]) : 0u);
      }
    }

#pragma unroll
    for (int sub = 0; sub < 2; ++sub) {
      // S^T[k][q] = K * Q^T ; lane holds S[q=lr][k = 4*lg + r (+16 for s1)]
      f32x4 s0 = __builtin_amdgcn_mfma_f32_16x16x32_bf16(kf0, qf[sub], zero4, 0, 0, 0);
      f32x4 s1 = __builtin_amdgcn_mfma_f32_16x16x32_bf16(kf1, qf[sub], zero4, 0, 0, 0);

      // elementwise tanh, pack bf16 pairs (k even|odd<<16)
      unsigned int u0 = f2bf_u(tanh_fast(CMUL * s0[0])) | (f2bf_u(tanh_fast(CMUL * s0[1])) << 16);
      unsigned int u1 = f2bf_u(tanh_fast(CMUL * s0[2])) | (f2bf_u(tanh_fast(CMUL * s0[3])) << 16);
      unsigned int u2 = f2bf_u(tanh_fast(CMUL * s1[0])) | (f2bf_u(tanh_fast(CMUL * s1[1])) << 16);
      unsigned int u3 = f2bf_u(tanh_fast(CMUL * s1[2])) | (f2bf_u(tanh_fast(CMUL * s1[3])) << 16);

      // Regroup: PV A-frag wants lane group G to hold k = 8G..8G+7.
      // Source quads live in lane groups {0,2} (srcA) / {1,3} (srcB);
      // G<2 takes the lo half (u0,u1), G>=2 the hi half (u2,u3).
      unsigned int a0A = (unsigned int)__shfl((int)u0, srcA, 64);
      unsigned int a1A = (unsigned int)__shfl((int)u1, srcA, 64);
      unsigned int a2A = (unsigned int)__shfl((int)u2, srcA, 64);
      unsigned int a3A = (unsigned int)__shfl((int)u3, srcA, 64);
      unsigned int a0B = (unsigned int)__shfl((int)u0, srcB, 64);
      unsigned int a1B = (unsigned int)__shfl((int)u1, srcB, 64);
      unsigned int a2B = (unsigned int)__shfl((int)u2, srcB, 64);
      unsigned int a3B = (unsigned int)__shfl((int)u3, srcB, 64);

      uint4v pw;
      pw[0] = hi ? a2A : a0A;
      pw[1] = hi ? a3A : a1A;
      pw[2] = hi ? a2B : a0B;
      pw[3] = hi ? a3B : a1B;
      short8 pa = __builtin_bit_cast(short8, pw);

      // O_tile += P[16q x 32k] * V[32k x 16d]
      acc[sub][0] = __builtin_amdgcn_mfma_f32_16x16x32_bf16(pa, vf0, acc[sub][0], 0, 0, 0);
      acc[sub][1] = __builtin_amdgcn_mfma_f32_16x16x32_bf16(pa, vf1, acc[sub][1], 0, 0, 0);
    }
  }

  // C/D layout: col = lane&15 (d), row = 4*lg + r (q within subtile)
#pragma unroll
  for (int sub = 0; sub < 2; ++sub)
#pragma unroll
    for (int ct = 0; ct < 2; ++ct)
#pragma unroll
      for (int r = 0; r < 4; ++r)
        part[w][sub * 16 + lg * 4 + r][ct * 16 + lr] = acc[sub][ct][r];

  __syncthreads();

  // Sum the 4 KV-chunk partials, write fp32 output [32 rows][24 d]
  float* Ob = Og + bh * S_LEN * HD + q0 * HD;
  for (int idx = tid; idx < 32 * HD; idx += 256) {
    const int row = idx / HD;
    const int d = idx - row * HD;
    Ob[idx] = part[0][row][d] + part[1][row][d] + part[2][row][d] + part[3][row][d];
  }
}

extern "C" void kernel_launch(void* const* d_in, const int* in_sizes, int n_in,
                              void* d_out, int out_size, void* d_ws, size_t ws_size,
                              hipStream_t stream) {
  (void)in_sizes; (void)n_in; (void)d_ws; (void)ws_size; (void)out_size;
  const float* Q = (const float*)d_in[0];
  const float* K = (const float*)d_in[1];
  const float* V = (const float*)d_in[2];
  // d_in[3] = attn_mask: the reference discards masked_fill's result, so it
  // has no effect on the output. Intentionally unread.
  float* O = (float*)d_out;

  dim3 grid(S_LEN / 32, 16);  // 64 q-tiles x (B*H)
  attn_tanh_fused<<<grid, 256, 0, stream>>>(Q, K, V, O);
}

// Round 4
// 331.694 us; speedup vs baseline: 1.1303x; 1.1303x over previous
//
#include <hip/hip_runtime.h>
#include <hip/hip_bf16.h>

// tanh-attention (no softmax): O = tanh(0.1/sqrt(24) * Q K^T) V
// B=2,H=8 -> 16 heads; S=2048; D=24 (padded to 32 for MFMA K-dim).
//
// Round-3 structure:
//   pre-pass A: Q -> bf16 [bh][2048][32], pre-scaled by 2*alpha*scale*log2(e)
//               (folds the tanh argument scaling into the MFMA)
//   pre-pass A: K -> bf16 [bh][2048][32] (zero-padded cols 24..31)
//   pre-pass B: V -> bf16 transposed [bh][32][2048] (zero rows 24..31)
//   main: swapped QK^T (S^T = K*Q^T) keeps P lane-local for elementwise tanh;
//         within-wave bpermute regroups P^T into the PV A-frag. All loads are
//         16B short8 vectors from the bf16 scratch; zero per-iter cvt of K/V.

#define S_LEN 2048
#define HD 24
#define CMUL 0.02041241452319315f                    // 0.1 / sqrt(24)
#define C2 (2.0f * CMUL * 1.4426950408889634f)       // fold 2x + log2(e) into Q

typedef short short8 __attribute__((ext_vector_type(8)));
typedef float f32x4 __attribute__((ext_vector_type(4)));
typedef unsigned int uint4v __attribute__((ext_vector_type(4)));

static __device__ __forceinline__ unsigned int pack_bf16(float a, float b) {
  // compiler lowers paired casts to v_cvt_pk_bf16_f32 (RNE)
  __hip_bfloat162 h = __float22bfloat162_rn(float2{a, b});
  unsigned int u;
  __builtin_memcpy(&u, &h, 4);
  return u;
}

static __device__ __forceinline__ float exp2_fast(float x) {
#if __has_builtin(__builtin_amdgcn_exp2f)
  return __builtin_amdgcn_exp2f(x);
#else
  return exp2f(x);
#endif
}

// tanh(m) where m2 = 2*m*log2(e) already applied upstream:
// t = e^{2m}; tanh = (t-1)/(t+1) = 1 - 2/(t+1).  |m| <~ 1.5 here -> no overflow.
static __device__ __forceinline__ float tanh1(float m2) {
  float t = exp2_fast(m2);
  float r = __builtin_amdgcn_rcpf(t + 1.f);
  return __builtin_fmaf(-2.f, r, 1.f);
}

// -------- pre-pass A: row-major fp32 [rows][24] -> bf16 [rows][32], scaled --------
extern "C" __global__ __launch_bounds__(256) void convert_pad_rows(
    const float* __restrict__ src, unsigned int* __restrict__ dst, float scale) {
  const int row = blockIdx.x * 256 + threadIdx.x;  // 16*2048 rows total
  const float* s = src + row * HD;
  float v[24];
#pragma unroll
  for (int i = 0; i < 6; ++i) {
    float4 x = *reinterpret_cast<const float4*>(s + i * 4);
    v[i * 4 + 0] = x.x; v[i * 4 + 1] = x.y; v[i * 4 + 2] = x.z; v[i * 4 + 3] = x.w;
  }
  uint4v o[4];
#pragma unroll
  for (int i = 0; i < 12; ++i)
    ((unsigned int*)o)[i] = pack_bf16(v[2 * i] * scale, v[2 * i + 1] * scale);
  o[3][0] = 0; o[3][1] = 0; o[3][2] = 0; o[3][3] = 0;  // pad cols 24..31
  uint4v* d = reinterpret_cast<uint4v*>(dst + row * 16);
  d[0] = o[0]; d[1] = o[1]; d[2] = o[2]; d[3] = o[3];
}

// -------- pre-pass B: V [bh][2048][24] fp32 -> Vt [bh][32][2048] bf16 --------
extern "C" __global__ __launch_bounds__(256) void transpose_v(
    const float* __restrict__ V, unsigned short* __restrict__ Vt) {
  __shared__ float lds[128][25];  // +1 pad: conflict-free column reads
  const int t = threadIdx.x;
  const int bh = blockIdx.y;
  const int kv0 = blockIdx.x * 128;
  const float* Vb = V + (bh * S_LEN + kv0) * HD;
  {
    const int r = t >> 1, c0 = (t & 1) * 12;  // 2 threads/row, 12 floats each
    const float* p = Vb + r * HD + c0;
#pragma unroll
    for (int i = 0; i < 3; ++i) {
      float4 x = *reinterpret_cast<const float4*>(p + i * 4);
      lds[r][c0 + i * 4 + 0] = x.x; lds[r][c0 + i * 4 + 1] = x.y;
      lds[r][c0 + i * 4 + 2] = x.z; lds[r][c0 + i * 4 + 3] = x.w;
    }
  }
  __syncthreads();
  const int d = t >> 3, seg = (t & 7) * 16;  // 32 d-rows x 8 segs of 16 kv
  unsigned int ob[8];
#pragma unroll
  for (int k = 0; k < 8; ++k) {
    float a = (d < HD) ? lds[seg + 2 * k][d] : 0.f;
    float b = (d < HD) ? lds[seg + 2 * k + 1][d] : 0.f;
    ob[k] = pack_bf16(a, b);
  }
  uint4v* dst = reinterpret_cast<uint4v*>(Vt + (bh * 32 + d) * S_LEN + kv0 + seg);
  dst[0] = *reinterpret_cast<uint4v*>(&ob[0]);
  dst[1] = *reinterpret_cast<uint4v*>(&ob[4]);
}

// -------- main fused kernel --------
extern "C" __global__ __launch_bounds__(256, 2) void attn_tanh_fused(
    const unsigned short* __restrict__ QsU, const unsigned short* __restrict__ KsU,
    const unsigned short* __restrict__ VtU, float* __restrict__ Og) {
  __shared__ float part[4][32][32];  // 16 KiB: per-wave fp32 partial O tiles

  const int tid = threadIdx.x;
  const int w   = tid >> 6;   // wave 0..3 -> KV chunk
  const int l   = tid & 63;
  const int lr  = l & 15;     // row-in-16
  const int lg  = l >> 4;     // lane group 0..3
  const int bh  = blockIdx.y;
  const int q0  = blockIdx.x * 32;

  const short8* Qp = reinterpret_cast<const short8*>(QsU) + bh * (S_LEN * 4);
  const short8* Kp = reinterpret_cast<const short8*>(KsU) + bh * (S_LEN * 4);
  const short8* Vp = reinterpret_cast<const short8*>(VtU) + bh * (32 * 256);

  // Q fragments (pre-scaled bf16), held all kernel
  short8 qf[2];
  qf[0] = Qp[(q0 + lr) * 4 + lg];
  qf[1] = Qp[(q0 + 16 + lr) * 4 + lg];

  const f32x4 zero4 = {0.f, 0.f, 0.f, 0.f};
  f32x4 acc[2][2];  // [q-sub][d-col-tile]
#pragma unroll
  for (int i = 0; i < 2; ++i)
#pragma unroll
    for (int j = 0; j < 2; ++j) acc[i][j] = zero4;

  const int kv0  = w * (S_LEN / 4);
  const int srcA = lr + ((lg & 1) << 5);  // quad-regroup shuffle sources
  const int srcB = srcA + 16;
  const bool hi  = (lg >> 1) != 0;

#pragma unroll 2
  for (int kt = kv0; kt < kv0 + S_LEN / 4; kt += 32) {
    short8 kf0 = Kp[(kt + lr) * 4 + lg];
    short8 kf1 = Kp[(kt + 16 + lr) * 4 + lg];
    // V B-frag: lane holds V[kt + 8*lg + j][dcol] = Vt[dcol][kt + 8*lg + j]
    short8 vf0 = Vp[lr * 256 + (kt >> 3) + lg];
    short8 vf1 = Vp[(16 + lr) * 256 + (kt >> 3) + lg];

#pragma unroll
    for (int sub = 0; sub < 2; ++sub) {
      // S^T = K * Q^T ; lane holds S[q=lr][k = 4*lg + r (+16 for s1)],
      // already scaled to 2*m*log2(e) via pre-scaled Q
      f32x4 s0 = __builtin_amdgcn_mfma_f32_16x16x32_bf16(kf0, qf[sub], zero4, 0, 0, 0);
      f32x4 s1 = __builtin_amdgcn_mfma_f32_16x16x32_bf16(kf1, qf[sub], zero4, 0, 0, 0);

      unsigned int u0 = pack_bf16(tanh1(s0[0]), tanh1(s0[1]));
      unsigned int u1 = pack_bf16(tanh1(s0[2]), tanh1(s0[3]));
      unsigned int u2 = pack_bf16(tanh1(s1[0]), tanh1(s1[1]));
      unsigned int u3 = pack_bf16(tanh1(s1[2]), tanh1(s1[3]));

      // Regroup: PV A-frag wants lane group G to hold k = 8G..8G+7.
      unsigned int a0A = (unsigned int)__shfl((int)u0, srcA, 64);
      unsigned int a1A = (unsigned int)__shfl((int)u1, srcA, 64);
      unsigned int a2A = (unsigned int)__shfl((int)u2, srcA, 64);
      unsigned int a3A = (unsigned int)__shfl((int)u3, srcA, 64);
      unsigned int a0B = (unsigned int)__shfl((int)u0, srcB, 64);
      unsigned int a1B = (unsigned int)__shfl((int)u1, srcB, 64);
      unsigned int a2B = (unsigned int)__shfl((int)u2, srcB, 64);
      unsigned int a3B = (unsigned int)__shfl((int)u3, srcB, 64);

      uint4v pw;
      pw[0] = hi ? a2A : a0A;
      pw[1] = hi ? a3A : a1A;
      pw[2] = hi ? a2B : a0B;
      pw[3] = hi ? a3B : a1B;
      short8 pa;
      __builtin_memcpy(&pa, &pw, 16);

      acc[sub][0] = __builtin_amdgcn_mfma_f32_16x16x32_bf16(pa, vf0, acc[sub][0], 0, 0, 0);
      acc[sub][1] = __builtin_amdgcn_mfma_f32_16x16x32_bf16(pa, vf1, acc[sub][1], 0, 0, 0);
    }
  }

  // C/D layout: col = lane&15 (d), row = 4*lg + r (q within subtile)
#pragma unroll
  for (int sub = 0; sub < 2; ++sub)
#pragma unroll
    for (int ct = 0; ct < 2; ++ct)
#pragma unroll
      for (int r = 0; r < 4; ++r)
        part[w][sub * 16 + lg * 4 + r][ct * 16 + lr] = acc[sub][ct][r];

  __syncthreads();

  float* Ob = Og + bh * S_LEN * HD + q0 * HD;
  for (int idx = tid; idx < 32 * HD; idx += 256) {
    const int row = idx / HD;
    const int d = idx - row * HD;
    Ob[idx] = part[0][row][d] + part[1][row][d] + part[2][row][d] + part[3][row][d];
  }
}

extern "C" void kernel_launch(void* const* d_in, const int* in_sizes, int n_in,
                              void* d_out, int out_size, void* d_ws, size_t ws_size,
                              hipStream_t stream) {
  (void)in_sizes; (void)n_in; (void)out_size; (void)ws_size;
  const float* Q = (const float*)d_in[0];
  const float* K = (const float*)d_in[1];
  const float* V = (const float*)d_in[2];
  // d_in[3] = attn_mask: reference discards masked_fill's result -> unread.
  float* O = (float*)d_out;

  // ws layout (bf16/ushort elems): Qs [16][2048][32] | Ks [16][2048][32] | Vt [16][32][2048]
  unsigned short* Qs = (unsigned short*)d_ws;
  unsigned short* Ks = Qs + 16 * S_LEN * 32;
  unsigned short* Vt = Ks + 16 * S_LEN * 32;

  convert_pad_rows<<<dim3(16 * S_LEN / 256), 256, 0, stream>>>(Q, (unsigned int*)Qs, C2);
  convert_pad_rows<<<dim3(16 * S_LEN / 256), 256, 0, stream>>>(K, (unsigned int*)Ks, 1.0f);
  transpose_v<<<dim3(S_LEN / 128, 16), 256, 0, stream>>>(V, Vt);

  dim3 grid(S_LEN / 32, 16);  // 64 q-tiles x (B*H)
  attn_tanh_fused<<<grid, 256, 0, stream>>>(Qs, Ks, Vt, O);
}

// Round 5
// 330.621 us; speedup vs baseline: 1.1340x; 1.0032x over previous
//
#include <hip/hip_runtime.h>
#include <hip/hip_bf16.h>

// tanh-attention (no softmax): O = tanh(0.1/sqrt(24) * Q K^T) V
// B=2,H=8 -> 16 heads; S=2048; D=24 (padded to 32 for MFMA K-dim).
//
// Round-5 structure:
//   ONE fused pre-pass kernel (512 blocks, block-uniform branch):
//     blocks   0..127: Q -> bf16 [bh][2048][32], pre-scaled by 2*alpha*scale*log2(e)
//     blocks 128..255: K -> bf16 [bh][2048][32] (zero-padded cols 24..31)
//     blocks 256..511: V -> bf16 transposed [bh][32][2048] (zero rows 24..31)
//   main: swapped QK^T (S^T = K*Q^T) keeps P lane-local for elementwise tanh;
//         within-wave shuffle regroups P^T into the PV A-frag. All loads are
//         16B short8 vectors from the bf16 scratch; zero per-iter cvt of K/V.

#define S_LEN 2048
#define HD 24
#define CMUL 0.02041241452319315f                    // 0.1 / sqrt(24)
#define C2 (2.0f * CMUL * 1.4426950408889634f)       // fold 2x + log2(e) into Q

typedef short short8 __attribute__((ext_vector_type(8)));
typedef float f32x4 __attribute__((ext_vector_type(4)));
typedef unsigned int uint4v __attribute__((ext_vector_type(4)));

static __device__ __forceinline__ unsigned int pack_bf16(float a, float b) {
  // compiler lowers paired casts to v_cvt_pk_bf16_f32 (RNE)
  __hip_bfloat162 h = __float22bfloat162_rn(float2{a, b});
  unsigned int u;
  __builtin_memcpy(&u, &h, 4);
  return u;
}

static __device__ __forceinline__ float exp2_fast(float x) {
#if __has_builtin(__builtin_amdgcn_exp2f)
  return __builtin_amdgcn_exp2f(x);
#else
  return exp2f(x);
#endif
}

// tanh(m) where m2 = 2*m*log2(e) already applied upstream:
// t = e^{2m}; tanh = (t-1)/(t+1) = 1 - 2/(t+1).  |m| small here -> no overflow,
// and exp2(+inf-ish) -> inf -> rcp -> 0 -> tanh -> 1 is still correct anyway.
static __device__ __forceinline__ float tanh1(float m2) {
  float t = exp2_fast(m2);
  float r = __builtin_amdgcn_rcpf(t + 1.f);
  return __builtin_fmaf(-2.f, r, 1.f);
}

// -------- fused pre-pass: Q/K convert+pad, V transpose --------
extern "C" __global__ __launch_bounds__(256) void prepass_fused(
    const float* __restrict__ Q, const float* __restrict__ K,
    const float* __restrict__ V, unsigned int* __restrict__ Qs,
    unsigned int* __restrict__ Ks, unsigned short* __restrict__ Vt) {
  __shared__ float lds[128][25];  // used by V-transpose blocks only
  const int b = blockIdx.x;
  const int t = threadIdx.x;

  if (b < 256) {
    // ---- convert+pad one row of Q or K (block-uniform select) ----
    const bool isQ = (b < 128);
    const int row = (isQ ? b : b - 128) * 256 + t;  // 16*2048 rows per tensor
    const float scale = isQ ? C2 : 1.0f;
    const float* s = (isQ ? Q : K) + row * HD;
    float v[24];
#pragma unroll
    for (int i = 0; i < 6; ++i) {
      float4 x = *reinterpret_cast<const float4*>(s + i * 4);
      v[i * 4 + 0] = x.x; v[i * 4 + 1] = x.y; v[i * 4 + 2] = x.z; v[i * 4 + 3] = x.w;
    }
    uint4v o[4];
#pragma unroll
    for (int i = 0; i < 12; ++i)
      ((unsigned int*)o)[i] = pack_bf16(v[2 * i] * scale, v[2 * i + 1] * scale);
    o[3][0] = 0; o[3][1] = 0; o[3][2] = 0; o[3][3] = 0;  // pad cols 24..31
    uint4v* d = reinterpret_cast<uint4v*>((isQ ? Qs : Ks) + row * 16);
    d[0] = o[0]; d[1] = o[1]; d[2] = o[2]; d[3] = o[3];
  } else {
    // ---- V [bh][2048][24] fp32 -> Vt [bh][32][2048] bf16, one 128-kv tile ----
    const int vb = b - 256;
    const int bh = vb >> 4;
    const int kv0 = (vb & 15) * 128;
    const float* Vb = V + (bh * S_LEN + kv0) * HD;
    {
      const int r = t >> 1, c0 = (t & 1) * 12;  // 2 threads/row, 12 floats each
      const float* p = Vb + r * HD + c0;
#pragma unroll
      for (int i = 0; i < 3; ++i) {
        float4 x = *reinterpret_cast<const float4*>(p + i * 4);
        lds[r][c0 + i * 4 + 0] = x.x; lds[r][c0 + i * 4 + 1] = x.y;
        lds[r][c0 + i * 4 + 2] = x.z; lds[r][c0 + i * 4 + 3] = x.w;
      }
    }
    __syncthreads();  // block-uniform branch: all 256 threads arrive
    const int d = t >> 3, seg = (t & 7) * 16;  // 32 d-rows x 8 segs of 16 kv
    unsigned int ob[8];
#pragma unroll
    for (int k = 0; k < 8; ++k) {
      float a = (d < HD) ? lds[seg + 2 * k][d] : 0.f;
      float bb = (d < HD) ? lds[seg + 2 * k + 1][d] : 0.f;
      ob[k] = pack_bf16(a, bb);
    }
    uint4v* dst = reinterpret_cast<uint4v*>(Vt + (bh * 32 + d) * S_LEN + kv0 + seg);
    dst[0] = *reinterpret_cast<uint4v*>(&ob[0]);
    dst[1] = *reinterpret_cast<uint4v*>(&ob[4]);
  }
}

// -------- main fused kernel (unchanged from round 4, validated) --------
extern "C" __global__ __launch_bounds__(256, 2) void attn_tanh_fused(
    const unsigned short* __restrict__ QsU, const unsigned short* __restrict__ KsU,
    const unsigned short* __restrict__ VtU, float* __restrict__ Og) {
  __shared__ float part[4][32][32];  // 16 KiB: per-wave fp32 partial O tiles

  const int tid = threadIdx.x;
  const int w   = tid >> 6;   // wave 0..3 -> KV chunk
  const int l   = tid & 63;
  const int lr  = l & 15;     // row-in-16
  const int lg  = l >> 4;     // lane group 0..3
  const int bh  = blockIdx.y;
  const int q0  = blockIdx.x * 32;

  const short8* Qp = reinterpret_cast<const short8*>(QsU) + bh * (S_LEN * 4);
  const short8* Kp = reinterpret_cast<const short8*>(KsU) + bh * (S_LEN * 4);
  const short8* Vp = reinterpret_cast<const short8*>(VtU) + bh * (32 * 256);

  // Q fragments (pre-scaled bf16), held all kernel
  short8 qf[2];
  qf[0] = Qp[(q0 + lr) * 4 + lg];
  qf[1] = Qp[(q0 + 16 + lr) * 4 + lg];

  const f32x4 zero4 = {0.f, 0.f, 0.f, 0.f};
  f32x4 acc[2][2];  // [q-sub][d-col-tile]
#pragma unroll
  for (int i = 0; i < 2; ++i)
#pragma unroll
    for (int j = 0; j < 2; ++j) acc[i][j] = zero4;

  const int kv0  = w * (S_LEN / 4);
  const int srcA = lr + ((lg & 1) << 5);  // quad-regroup shuffle sources
  const int srcB = srcA + 16;
  const bool hi  = (lg >> 1) != 0;

#pragma unroll 2
  for (int kt = kv0; kt < kv0 + S_LEN / 4; kt += 32) {
    short8 kf0 = Kp[(kt + lr) * 4 + lg];
    short8 kf1 = Kp[(kt + 16 + lr) * 4 + lg];
    // V B-frag: lane holds V[kt + 8*lg + j][dcol] = Vt[dcol][kt + 8*lg + j]
    short8 vf0 = Vp[lr * 256 + (kt >> 3) + lg];
    short8 vf1 = Vp[(16 + lr) * 256 + (kt >> 3) + lg];

#pragma unroll
    for (int sub = 0; sub < 2; ++sub) {
      // S^T = K * Q^T ; lane holds S[q=lr][k = 4*lg + r (+16 for s1)],
      // already scaled to 2*m*log2(e) via pre-scaled Q
      f32x4 s0 = __builtin_amdgcn_mfma_f32_16x16x32_bf16(kf0, qf[sub], zero4, 0, 0, 0);
      f32x4 s1 = __builtin_amdgcn_mfma_f32_16x16x32_bf16(kf1, qf[sub], zero4, 0, 0, 0);

      unsigned int u0 = pack_bf16(tanh1(s0[0]), tanh1(s0[1]));
      unsigned int u1 = pack_bf16(tanh1(s0[2]), tanh1(s0[3]));
      unsigned int u2 = pack_bf16(tanh1(s1[0]), tanh1(s1[1]));
      unsigned int u3 = pack_bf16(tanh1(s1[2]), tanh1(s1[3]));

      // Regroup: PV A-frag wants lane group G to hold k = 8G..8G+7.
      unsigned int a0A = (unsigned int)__shfl((int)u0, srcA, 64);
      unsigned int a1A = (unsigned int)__shfl((int)u1, srcA, 64);
      unsigned int a2A = (unsigned int)__shfl((int)u2, srcA, 64);
      unsigned int a3A = (unsigned int)__shfl((int)u3, srcA, 64);
      unsigned int a0B = (unsigned int)__shfl((int)u0, srcB, 64);
      unsigned int a1B = (unsigned int)__shfl((int)u1, srcB, 64);
      unsigned int a2B = (unsigned int)__shfl((int)u2, srcB, 64);
      unsigned int a3B = (unsigned int)__shfl((int)u3, srcB, 64);

      uint4v pw;
      pw[0] = hi ? a2A : a0A;
      pw[1] = hi ? a3A : a1A;
      pw[2] = hi ? a2B : a0B;
      pw[3] = hi ? a3B : a1B;
      short8 pa;
      __builtin_memcpy(&pa, &pw, 16);

      acc[sub][0] = __builtin_amdgcn_mfma_f32_16x16x32_bf16(pa, vf0, acc[sub][0], 0, 0, 0);
      acc[sub][1] = __builtin_amdgcn_mfma_f32_16x16x32_bf16(pa, vf1, acc[sub][1], 0, 0, 0);
    }
  }

  // C/D layout: col = lane&15 (d), row = 4*lg + r (q within subtile)
#pragma unroll
  for (int sub = 0; sub < 2; ++sub)
#pragma unroll
    for (int ct = 0; ct < 2; ++ct)
#pragma unroll
      for (int r = 0; r < 4; ++r)
        part[w][sub * 16 + lg * 4 + r][ct * 16 + lr] = acc[sub][ct][r];

  __syncthreads();

  float* Ob = Og + bh * S_LEN * HD + q0 * HD;
  for (int idx = tid; idx < 32 * HD; idx += 256) {
    const int row = idx / HD;
    const int d = idx - row * HD;
    Ob[idx] = part[0][row][d] + part[1][row][d] + part[2][row][d] + part[3][row][d];
  }
}

extern "C" void kernel_launch(void* const* d_in, const int* in_sizes, int n_in,
                              void* d_out, int out_size, void* d_ws, size_t ws_size,
                              hipStream_t stream) {
  (void)in_sizes; (void)n_in; (void)out_size; (void)ws_size;
  const float* Q = (const float*)d_in[0];
  const float* K = (const float*)d_in[1];
  const float* V = (const float*)d_in[2];
  // d_in[3] = attn_mask: reference discards masked_fill's result -> unread.
  float* O = (float*)d_out;

  // ws layout (bf16/ushort elems): Qs [16][2048][32] | Ks [16][2048][32] | Vt [16][32][2048]
  unsigned short* Qs = (unsigned short*)d_ws;
  unsigned short* Ks = Qs + 16 * S_LEN * 32;
  unsigned short* Vt = Ks + 16 * S_LEN * 32;

  prepass_fused<<<dim3(512), 256, 0, stream>>>(Q, K, V, (unsigned int*)Qs,
                                               (unsigned int*)Ks, Vt);

  dim3 grid(S_LEN / 32, 16);  // 64 q-tiles x (B*H)
  attn_tanh_fused<<<grid, 256, 0, stream>>>(Qs, Ks, Vt, O);
}